// Round 16
// baseline (296.989 us; speedup 1.0000x reference)
//
#include <hip/hip_runtime.h>
#include <hip/hip_bf16.h>
#include <hip/hip_fp16.h>

#define DD    128
#define VOCAB 2048
#define NRELS 7
#define NWF   (130 * 16384)   // W frag-layout elements: 128 kron + l + r chunks

typedef _Float16 f16;
typedef __attribute__((ext_vector_type(8))) _Float16 f16x8;
typedef __attribute__((ext_vector_type(4))) float    f32x4;

// flexible-dtype load: bf==1 -> bf16 storage, bf==0 -> f32 storage
__device__ __forceinline__ float lde(const void* p, size_t i, int bf) {
    if (bf) return (float)((const __hip_bfloat16*)p)[i];
    return ((const float*)p)[i];
}

// detect storage dtype by exponent-field sanity of Wv's first 64 uint16s
__device__ __forceinline__ int detect_bf(const unsigned short* wv) {
    int sane = 0;
    #pragma unroll
    for (int i = 0; i < 64; ++i) {
        unsigned e = (wv[i] >> 7) & 0xFFu;
        sane += (e >= 90u && e <= 160u) ? 1 : 0;
    }
    return sane == 64;
}

// ---------------------------------------------------------------------------
// prep_all: WvT transpose, W frag-major repack (NT stores: write-once data),
// biases. Frag layout: Wf[((i*8+n8)*4+t)*512 + ln*8 + e] =
//                      W[n8*16+(ln&15)][i*128 + t*32 + (ln>>4)*8 + e]
// ---------------------------------------------------------------------------
__global__ void prep_all(const void* Wv, const void* bv,
                         const void* Wcps, const void* bcps,
                         const void* Wcpst, const void* bcpst,
                         const void* Wcpr, const void* bcpr,
                         const void* Wcprt, const void* bcprt,
                         const void* Wsm, const void* bsm,
                         f16* __restrict__ WvT, f16* __restrict__ Wext, f16* __restrict__ Wfin,
                         float* __restrict__ bias_lvl, float* __restrict__ bias_fin,
                         float* __restrict__ Wsm_f, float* __restrict__ bsm_f)
{
    const int bf = detect_bf((const unsigned short*)Wv);
    const int b = blockIdx.x;
    const int tid = threadIdx.x;

    if (b < 64) {                     // ---- WvT transpose ----
        __shared__ float tile[64][65];
        int vt = b >> 1, dt = b & 1;
        int tx = tid & 63, ty = tid >> 6;
        for (int yy = ty; yy < 64; yy += 4)
            tile[yy][tx] = lde(Wv, (size_t)(dt * 64 + yy) * VOCAB + vt * 64 + tx, bf);
        __syncthreads();
        for (int yy = ty; yy < 64; yy += 4) {
            int v = vt * 64 + yy, d = dt * 64 + tx;
            __builtin_nontemporal_store((f16)(tile[tx][yy] + lde(bv, d, bf)),
                                        &WvT[(size_t)v * DD + d]);
        }
        return;
    }
    if (b >= 2144) {                  // ---- biases + softmax weights ----
        if (tid < 128)      bias_lvl[tid] = lde(bcps, tid, bf) + lde(bcpst, tid, bf);
        else if (tid < 256) bias_fin[tid - 128] = lde(bcpr, tid - 128, bf) + lde(bcprt, tid - 128, bf);
        for (int o = tid; o < NRELS * DD; o += 256) Wsm_f[o] = lde(Wsm, o, bf);
        if (tid < NRELS) bsm_f[tid] = lde(bsm, tid, bf);
        return;
    }
    // ---- W frag repack ----
    const int bb    = b - 64;
    const int which = bb / 1040;      // 0: ext, 1: fin
    const int rem   = bb - which * 1040;
    const int i     = rem >> 3;       // 0..129
    const int n8    = rem & 7;
    const void* Wt = which ? (const void*)Wcprt : (const void*)Wcpst;
    const void* Ws = which ? (const void*)Wcpr  : (const void*)Wcps;
    f16* dst = which ? Wfin : Wext;

    __shared__ float tile[16 * 129];
    #pragma unroll
    for (int it = 0; it < 8; ++it) {
        int idx = it * 256 + tid;
        int rr = idx >> 7, c = idx & 127;
        float v = (i < 128) ? lde(Wt, (size_t)(n8 * 16 + rr) * 16384 + (size_t)i * 128 + c, bf)
                            : lde(Ws, (size_t)(n8 * 16 + rr) * 256 + (size_t)(i - 128) * 128 + c, bf);
        tile[rr * 129 + c] = v;
    }
    __syncthreads();
    f16* out = dst + (size_t)(i * 8 + n8) * 2048;
    #pragma unroll
    for (int it = 0; it < 8; ++it) {
        int o = it * 256 + tid;
        int t = o >> 9, ln = (o >> 3) & 63, e = o & 7;
        __builtin_nontemporal_store((f16)tile[(ln & 15) * 129 + t * 32 + ((ln >> 4) << 3) + e],
                                    &out[o]);
    }
}

// ---------------------------------------------------------------------------
// GEMM over A_ext = [kron(l,r) | l | r] vs W, split-K over kron rows i.
// R13 structure (best measured): block = 256 threads = 4 waves x 64 rows ->
// 256-row x 64-col tile, one 16 KB W chunk per stage through a 32 KB LDS
// double-buffer via global_load_lds, barrier every stage.
// launch_bounds(256,2): hard floor — (256,3)/(256,4) both spill (R12/R14).
// XCD-pinned n-half (nh=(b>>2)&1). s==1 appends lin-l (i=128), s==2 lin-r
// (i=129). Partials f16 -> part[s][p][n].
// ---------------------------------------------------------------------------
template<int BI>
__launch_bounds__(256, 2)
__global__ void gemm_kernel(const f16* __restrict__ hin, const int* __restrict__ ids,
                            const f16* __restrict__ Wf,
                            f16* __restrict__ part, int Mrows, int S)
{
    __shared__ f16 Wb[2][8192];         // 32 KB: dbuf of one (i, nh) chunk

    const int tid  = threadIdx.x;
    const int lane = tid & 63;
    const int wv   = tid >> 6;                     // 0..3
    const int b    = blockIdx.x;
    const int nh   = (b >> 2) & 1;                 // XCD-half -> n-half
    const int r    = ((b >> 3) << 2) | (b & 3);
    const int mb   = r / S;
    const int s    = r - mb * S;
    const int m0   = mb * 256;
    const int i0   = s * BI;
    const bool tail = (s == 1 || s == 2);

    const int mrow = lane & 15;
    const int q    = lane >> 4;
    const int wm   = wv * 64;

    // ---- r fragments (A-layout) for this wave's 64 rows ----
    f16x8 rf[4][4];
    int rowL[4];
    #pragma unroll
    for (int mt = 0; mt < 4; ++mt) {
        int p = m0 + wm + mt * 16 + mrow;
        int row = ids ? ids[2 * p + 1] : 2 * p + 1;
        rowL[mt] = ids ? ids[2 * p] : 2 * p;
        #pragma unroll
        for (int t = 0; t < 4; ++t)
            rf[mt][t] = *(const f16x8*)&hin[(size_t)row * DD + t * 32 + q * 8];
    }

    // ---- l-window: this lane's 4 rows, halves [i0, i0+BI) in registers ----
    f16 lw[4][BI];
    #pragma unroll
    for (int mt = 0; mt < 4; ++mt) {
        const f16* src = &hin[(size_t)rowL[mt] * DD + i0];
        if constexpr (BI == 16) { *(f16x8*)&lw[mt][0] = *(const f16x8*)src;
                                  *(f16x8*)&lw[mt][8] = *(const f16x8*)(src + 8); }
        else if constexpr (BI == 8) { *(f16x8*)&lw[mt][0] = *(const f16x8*)src; }
        else if constexpr (BI == 4) { *(unsigned long long*)&lw[mt][0] = *(const unsigned long long*)src; }
        else if constexpr (BI == 2) { *(unsigned int*)&lw[mt][0] = *(const unsigned int*)src; }
        else { lw[mt][0] = src[0]; }
    }

    // ---- async W staging: one (i, nh) 16 KB chunk -> Wb[buf] ----
    auto stage = [&](int i, int buf) {
        const f16* g = Wf + (size_t)i * 16384 + nh * 8192;
        #pragma unroll
        for (int k = 0; k < 4; ++k) {
            int j = k * 4 + wv;                    // 0..15
            const f16* gg = g + (size_t)(j * 64 + lane) * 8;
            f16* l = &Wb[buf][(size_t)(j * 64) * 8];
            __builtin_amdgcn_global_load_lds(
                (const __attribute__((address_space(1))) unsigned int*)gg,
                (__attribute__((address_space(3))) unsigned int*)l, 16, 0, 0);
        }
    };

    stage(i0, 0);
    __syncthreads();

    f32x4 acc[4][4] = {};

    // one t-step: A = a-frags (lb*rf or rf), B = 4 frags from LDS
#define TSTEP(T, BUF, KRON, LBV)                                                        \
    {                                                                                   \
        f16x8 wc[4];                                                                    \
        _Pragma("unroll")                                                               \
        for (int nt = 0; nt < 4; ++nt)                                                  \
            wc[nt] = *(const f16x8*)&Wb[BUF][nt * 2048 + (T) * 512 + lane * 8];         \
        _Pragma("unroll")                                                               \
        for (int mt = 0; mt < 4; ++mt) {                                                \
            f16x8 a = (KRON) ? (LBV[mt] * rf[mt][T]) : rf[mt][T];                       \
            _Pragma("unroll")                                                           \
            for (int nt = 0; nt < 4; ++nt)                                              \
                acc[mt][nt] = __builtin_amdgcn_mfma_f32_16x16x32_f16(a, wc[nt], acc[mt][nt], 0, 0, 0); \
        }                                                                               \
    }

    #pragma unroll
    for (int ii = 0; ii < BI; ++ii) {
        const int buf = ii & 1;
        // prefetch next chunk into other buffer
        if (ii + 1 < BI)      stage(i0 + ii + 1, buf ^ 1);
        else if (tail)        stage(s == 1 ? 128 : 129, buf ^ 1);
        // broadcast l values for this i (static lw index)
        f16x8 lb[4];
        #pragma unroll
        for (int mt = 0; mt < 4; ++mt) {
            f16 v = lw[mt][ii];
            #pragma unroll
            for (int e = 0; e < 8; ++e) lb[mt][e] = v;
        }
        TSTEP(0, buf, true, lb); TSTEP(1, buf, true, lb);
        TSTEP(2, buf, true, lb); TSTEP(3, buf, true, lb);
        __syncthreads();
    }

    if (tail) {
        const int buf = BI & 1;
        if (s == 1) {       // lin-l: overwrite rf with l-row A-frags
            #pragma unroll
            for (int mt = 0; mt < 4; ++mt)
                #pragma unroll
                for (int t = 0; t < 4; ++t)
                    rf[mt][t] = *(const f16x8*)&hin[(size_t)rowL[mt] * DD + t * 32 + q * 8];
        }
        f16x8 dummy[4];
        TSTEP(0, buf, false, dummy); TSTEP(1, buf, false, dummy);
        TSTEP(2, buf, false, dummy); TSTEP(3, buf, false, dummy);
    }
#undef TSTEP

    // ---- store f16 partial tile: C/D layout col=lane&15, row=q*4+reg ----
    f16* pb = part + ((size_t)s * Mrows + m0) * DD + nh * 64;
    #pragma unroll
    for (int mt = 0; mt < 4; ++mt)
        #pragma unroll
        for (int nt = 0; nt < 4; ++nt) {
            int colg = nt * 16 + mrow;
            #pragma unroll
            for (int rr = 0; rr < 4; ++rr) {
                int rowl = wm + mt * 16 + q * 4 + rr;
                pb[(size_t)rowl * DD + colg] = (f16)acc[mt][nt][rr];
            }
        }
}

// ---------------------------------------------------------------------------
// level epilogue: h_out = f16(tanh(sum_s part[s] + bias))
// ---------------------------------------------------------------------------
__global__ void epi_level(const f16* __restrict__ part, const float* __restrict__ bias,
                          f16* __restrict__ hout, int Mrows, int S)
{
    int idx = (blockIdx.x * 256 + threadIdx.x) * 8;
    size_t stride = (size_t)Mrows * DD;
    float sum[8] = {};
    for (int s2 = 0; s2 < S; ++s2) {
        f16x8 v = *(const f16x8*)&part[(size_t)s2 * stride + idx];
        #pragma unroll
        for (int e = 0; e < 8; ++e) sum[e] += (float)v[e];
    }
    int n = idx & 127;
    f16x8 o;
    #pragma unroll
    for (int e = 0; e < 8; ++e) o[e] = (f16)tanhf(sum[e] + bias[n + e]);
    *(f16x8*)&hout[idx] = o;
}

// ---------------------------------------------------------------------------
// final epilogue: leaky_relu(sum_s part + bias) @ Wsm^T + bsm -> log_softmax
// ---------------------------------------------------------------------------
__global__ void fin_epi(const f16* __restrict__ part, const float* __restrict__ bias,
                        const float* __restrict__ Wsm_f, const float* __restrict__ bsm_f,
                        const unsigned short* __restrict__ wv_raw, void* __restrict__ outp, int S)
{
    int lane = threadIdx.x & 63;
    int wv = threadIdx.x >> 6;
    int p = blockIdx.x * 4 + wv;              // 0..511
    size_t stride = (size_t)512 * DD;
    const f16* base = part + (size_t)p * DD;
    float a0 = 0.f, a1 = 0.f;
    for (int s2 = 0; s2 < S; ++s2) {
        a0 += (float)base[(size_t)s2 * stride + lane];
        a1 += (float)base[(size_t)s2 * stride + 64 + lane];
    }
    a0 += bias[lane];      a1 += bias[64 + lane];
    a0 = (a0 > 0.f) ? a0 : 0.01f * a0;
    a1 = (a1 > 0.f) ? a1 : 0.01f * a1;
    float lg[NRELS];
    #pragma unroll
    for (int r = 0; r < NRELS; ++r) {
        float pr = a0 * Wsm_f[r * DD + lane] + a1 * Wsm_f[r * DD + 64 + lane];
        #pragma unroll
        for (int d = 1; d < 64; d <<= 1) pr += __shfl_xor(pr, d, 64);
        lg[r] = pr + bsm_f[r];
    }
    float mx = lg[0];
    #pragma unroll
    for (int r = 1; r < NRELS; ++r) mx = fmaxf(mx, lg[r]);
    float se = 0.f;
    #pragma unroll
    for (int r = 0; r < NRELS; ++r) se += expf(lg[r] - mx);
    float lse = logf(se) + mx;
    if (lane < NRELS) {
        float v = lg[lane] - lse;
        if (detect_bf(wv_raw)) ((__hip_bfloat16*)outp)[p * NRELS + lane] = __float2bfloat16(v);
        else                   ((float*)outp)[p * NRELS + lane] = v;
    }
}

// ---------------------------------------------------------------------------
extern "C" void kernel_launch(void* const* d_in, const int* in_sizes, int n_in,
                              void* d_out, int out_size, void* d_ws, size_t ws_size,
                              hipStream_t stream)
{
    const int* ids = (const int*)d_in[0];

    char* ws = (char*)d_ws;
    f16*   part     = (f16*)ws;                                      // 32 MiB region (f16 partials)
    f16*   h1       = (f16*)(ws + ((size_t)32 << 20));               // 2 MiB
    f16*   h2       = (f16*)(ws + ((size_t)34 << 20));               // 1 MiB
    f16*   h3       = (f16*)(ws + ((size_t)35 << 20));               // 0.5 MiB
    f16*   h4       = (f16*)(ws + ((size_t)35 << 20) + (512 << 10)); // 0.25 MiB
    f16*   WvT      = (f16*)(ws + ((size_t)36 << 20));               // 0.5 MiB
    f16*   Wext     = (f16*)(ws + ((size_t)36 << 20) + (512 << 10)); // 4.0625 MiB
    f16*   Wfin     = Wext + (size_t)NWF;                            // 4.0625 MiB
    float* bias_lvl = (float*)(Wfin + (size_t)NWF);
    float* bias_fin = bias_lvl + 128;
    float* Wsm_f    = bias_fin + 128;
    float* bsm_f    = Wsm_f + NRELS * DD;

    if (ws_size < ((size_t)48 << 20)) return;

    prep_all<<<2145, 256, 0, stream>>>(d_in[1], d_in[2], d_in[3], d_in[4], d_in[5], d_in[6],
                                       d_in[7], d_in[8], d_in[9], d_in[10], d_in[11], d_in[12],
                                       WvT, Wext, Wfin, bias_lvl, bias_fin, Wsm_f, bsm_f);

    // level 1 (fused embed-gather): M=8192, 32 mtiles(256) x S=8 x 2 nh -> 512
    // BI=16 halves staging redundancy vs R13's BI=8/1024-block split (R15
    // evidence: L1 dropped below 41 us) while keeping R13's K-loop intact.
    gemm_kernel<16><<<512, 256, 0, stream>>>(WvT, ids, Wext, part, 8192, 8);
    epi_level<<<512, 256, 0, stream>>>(part, bias_lvl, h1, 8192, 8);
    // level 2: M=4096, 16 mtiles x S=16 x 2 -> 512
    gemm_kernel<8><<<512, 256, 0, stream>>>(h1, nullptr, Wext, part, 4096, 16);
    epi_level<<<256, 256, 0, stream>>>(part, bias_lvl, h2, 4096, 16);
    // level 3: M=2048, 8 mtiles x S=32 x 2 -> 512
    gemm_kernel<4><<<512, 256, 0, stream>>>(h2, nullptr, Wext, part, 2048, 32);
    epi_level<<<128, 256, 0, stream>>>(part, bias_lvl, h3, 2048, 32);
    // level 4: M=1024, 4 mtiles x S=64 x 2 -> 512
    gemm_kernel<2><<<512, 256, 0, stream>>>(h3, nullptr, Wext, part, 1024, 64);
    epi_level<<<64, 256, 0, stream>>>(part, bias_lvl, h4, 1024, 64);
    // final: M=512, 2 mtiles x S=128 x 2 -> 512
    gemm_kernel<1><<<512, 256, 0, stream>>>(h4, nullptr, Wfin, part, 512, 128);
    fin_epi<<<128, 256, 0, stream>>>(part, bias_fin, Wsm_f, bsm_f,
                                     (const unsigned short*)d_in[1], d_out, 128);
}

// Round 17
// 258.069 us; speedup vs baseline: 1.1508x; 1.1508x over previous
//
#include <hip/hip_runtime.h>
#include <hip/hip_bf16.h>
#include <hip/hip_fp16.h>

#define DD    128
#define VOCAB 2048
#define NRELS 7
#define NWF   (130 * 16384)   // W frag-layout elements: 128 kron + l + r chunks

typedef _Float16 f16;
typedef __attribute__((ext_vector_type(8))) _Float16 f16x8;
typedef __attribute__((ext_vector_type(4))) float    f32x4;

// flexible-dtype load: bf==1 -> bf16 storage, bf==0 -> f32 storage
__device__ __forceinline__ float lde(const void* p, size_t i, int bf) {
    if (bf) return (float)((const __hip_bfloat16*)p)[i];
    return ((const float*)p)[i];
}

// detect storage dtype by exponent-field sanity of Wv's first 64 uint16s
__device__ __forceinline__ int detect_bf(const unsigned short* wv) {
    int sane = 0;
    #pragma unroll
    for (int i = 0; i < 64; ++i) {
        unsigned e = (wv[i] >> 7) & 0xFFu;
        sane += (e >= 90u && e <= 160u) ? 1 : 0;
    }
    return sane == 64;
}

// ---------------------------------------------------------------------------
// prep_all: WvT transpose, W frag-major repack (NT stores: write-once data),
// biases. Frag layout: Wf[((i*8+n8)*4+t)*512 + ln*8 + e] =
//                      W[n8*16+(ln&15)][i*128 + t*32 + (ln>>4)*8 + e]
// ---------------------------------------------------------------------------
__global__ void prep_all(const void* Wv, const void* bv,
                         const void* Wcps, const void* bcps,
                         const void* Wcpst, const void* bcpst,
                         const void* Wcpr, const void* bcpr,
                         const void* Wcprt, const void* bcprt,
                         const void* Wsm, const void* bsm,
                         f16* __restrict__ WvT, f16* __restrict__ Wext, f16* __restrict__ Wfin,
                         float* __restrict__ bias_lvl, float* __restrict__ bias_fin,
                         float* __restrict__ Wsm_f, float* __restrict__ bsm_f)
{
    const int bf = detect_bf((const unsigned short*)Wv);
    const int b = blockIdx.x;
    const int tid = threadIdx.x;

    if (b < 64) {                     // ---- WvT transpose ----
        __shared__ float tile[64][65];
        int vt = b >> 1, dt = b & 1;
        int tx = tid & 63, ty = tid >> 6;
        for (int yy = ty; yy < 64; yy += 4)
            tile[yy][tx] = lde(Wv, (size_t)(dt * 64 + yy) * VOCAB + vt * 64 + tx, bf);
        __syncthreads();
        for (int yy = ty; yy < 64; yy += 4) {
            int v = vt * 64 + yy, d = dt * 64 + tx;
            __builtin_nontemporal_store((f16)(tile[tx][yy] + lde(bv, d, bf)),
                                        &WvT[(size_t)v * DD + d]);
        }
        return;
    }
    if (b >= 2144) {                  // ---- biases + softmax weights ----
        if (tid < 128)      bias_lvl[tid] = lde(bcps, tid, bf) + lde(bcpst, tid, bf);
        else if (tid < 256) bias_fin[tid - 128] = lde(bcpr, tid - 128, bf) + lde(bcprt, tid - 128, bf);
        for (int o = tid; o < NRELS * DD; o += 256) Wsm_f[o] = lde(Wsm, o, bf);
        if (tid < NRELS) bsm_f[tid] = lde(bsm, tid, bf);
        return;
    }
    // ---- W frag repack ----
    const int bb    = b - 64;
    const int which = bb / 1040;      // 0: ext, 1: fin
    const int rem   = bb - which * 1040;
    const int i     = rem >> 3;       // 0..129
    const int n8    = rem & 7;
    const void* Wt = which ? (const void*)Wcprt : (const void*)Wcpst;
    const void* Ws = which ? (const void*)Wcpr  : (const void*)Wcps;
    f16* dst = which ? Wfin : Wext;

    __shared__ float tile[16 * 129];
    #pragma unroll
    for (int it = 0; it < 8; ++it) {
        int idx = it * 256 + tid;
        int rr = idx >> 7, c = idx & 127;
        float v = (i < 128) ? lde(Wt, (size_t)(n8 * 16 + rr) * 16384 + (size_t)i * 128 + c, bf)
                            : lde(Ws, (size_t)(n8 * 16 + rr) * 256 + (size_t)(i - 128) * 128 + c, bf);
        tile[rr * 129 + c] = v;
    }
    __syncthreads();
    f16* out = dst + (size_t)(i * 8 + n8) * 2048;
    #pragma unroll
    for (int it = 0; it < 8; ++it) {
        int o = it * 256 + tid;
        int t = o >> 9, ln = (o >> 3) & 63, e = o & 7;
        __builtin_nontemporal_store((f16)tile[(ln & 15) * 129 + t * 32 + ((ln >> 4) << 3) + e],
                                    &out[o]);
    }
}

// ---------------------------------------------------------------------------
// GEMM over A_ext = [kron(l,r) | l | r] vs W, split-K over kron rows i.
// Block = 256 threads = 4 waves x 64 rows -> 256-row x 64-col tile, sharing
// one 16 KB W chunk per stage. W staged through a FOUR-slot 64 KB LDS ring
// via global_load_lds: prefetch issued 2 stages ahead, __syncthreads only
// after odd stages (R15 evidence: halved barriers beat the dbuf at equal
// grids). Race-safety: consecutive stages always contain an odd one, so
// every slot's issue->use and read->rewrite windows cross a barrier; tail
// chunk (slot BI&3) is staged >=1 barrier before its post-loop use.
// launch_bounds(256,2): hard floor — (256,3)/(256,4) both spill (R12/R14).
// XCD-pinned n-half (nh=(b>>2)&1). s==1 appends lin-l (i=128), s==2 lin-r
// (i=129). Partials f16 -> part[s][p][n].
// ---------------------------------------------------------------------------
template<int BI>
__launch_bounds__(256, 2)
__global__ void gemm_kernel(const f16* __restrict__ hin, const int* __restrict__ ids,
                            const f16* __restrict__ Wf,
                            f16* __restrict__ part, int Mrows, int S)
{
    __shared__ f16 Wb[4][8192];         // 64 KB: 4-slot ring of 16 KB chunks

    const int tid  = threadIdx.x;
    const int lane = tid & 63;
    const int wv   = tid >> 6;                     // 0..3
    const int b    = blockIdx.x;
    const int nh   = (b >> 2) & 1;                 // XCD-half -> n-half
    const int r    = ((b >> 3) << 2) | (b & 3);
    const int mb   = r / S;
    const int s    = r - mb * S;
    const int m0   = mb * 256;
    const int i0   = s * BI;
    const bool tail = (s == 1 || s == 2);
    const int itail = (s == 1) ? 128 : 129;

    const int mrow = lane & 15;
    const int q    = lane >> 4;
    const int wm   = wv * 64;

    // ---- r fragments (A-layout) for this wave's 64 rows ----
    f16x8 rf[4][4];
    int rowL[4];
    #pragma unroll
    for (int mt = 0; mt < 4; ++mt) {
        int p = m0 + wm + mt * 16 + mrow;
        int row = ids ? ids[2 * p + 1] : 2 * p + 1;
        rowL[mt] = ids ? ids[2 * p] : 2 * p;
        #pragma unroll
        for (int t = 0; t < 4; ++t)
            rf[mt][t] = *(const f16x8*)&hin[(size_t)row * DD + t * 32 + q * 8];
    }

    // ---- l-window: this lane's 4 rows, halves [i0, i0+BI) in registers ----
    f16 lw[4][BI];
    #pragma unroll
    for (int mt = 0; mt < 4; ++mt) {
        const f16* src = &hin[(size_t)rowL[mt] * DD + i0];
        if constexpr (BI == 16) { *(f16x8*)&lw[mt][0] = *(const f16x8*)src;
                                  *(f16x8*)&lw[mt][8] = *(const f16x8*)(src + 8); }
        else if constexpr (BI == 8) { *(f16x8*)&lw[mt][0] = *(const f16x8*)src; }
        else if constexpr (BI == 4) { *(unsigned long long*)&lw[mt][0] = *(const unsigned long long*)src; }
        else if constexpr (BI == 2) { *(unsigned int*)&lw[mt][0] = *(const unsigned int*)src; }
        else { lw[mt][0] = src[0]; }
    }

    // ---- async W staging: one (i, nh) 16 KB chunk -> ring slot ----
    auto stage = [&](int i, int slot) {
        const f16* g = Wf + (size_t)i * 16384 + nh * 8192;
        #pragma unroll
        for (int k = 0; k < 4; ++k) {
            int j = k * 4 + wv;                    // 0..15
            const f16* gg = g + (size_t)(j * 64 + lane) * 8;
            f16* l = &Wb[slot][(size_t)(j * 64) * 8];
            __builtin_amdgcn_global_load_lds(
                (const __attribute__((address_space(1))) unsigned int*)gg,
                (__attribute__((address_space(3))) unsigned int*)l, 16, 0, 0);
        }
    };

    // preload stages 0 and 1
    stage(i0, 0);
    if (BI > 1)       stage(i0 + 1, 1);
    else if (tail)    stage(itail, 1);
    __syncthreads();

    f32x4 acc[4][4] = {};

    // one t-step: A = a-frags (lb*rf or rf), B = 4 frags from LDS slot
#define TSTEP(T, SLOT, KRON, LBV)                                                       \
    {                                                                                   \
        f16x8 wc[4];                                                                    \
        _Pragma("unroll")                                                               \
        for (int nt = 0; nt < 4; ++nt)                                                  \
            wc[nt] = *(const f16x8*)&Wb[SLOT][nt * 2048 + (T) * 512 + lane * 8];        \
        _Pragma("unroll")                                                               \
        for (int mt = 0; mt < 4; ++mt) {                                                \
            f16x8 a = (KRON) ? (LBV[mt] * rf[mt][T]) : rf[mt][T];                       \
            _Pragma("unroll")                                                           \
            for (int nt = 0; nt < 4; ++nt)                                              \
                acc[mt][nt] = __builtin_amdgcn_mfma_f32_16x16x32_f16(a, wc[nt], acc[mt][nt], 0, 0, 0); \
        }                                                                               \
    }

    #pragma unroll
    for (int ii = 0; ii < BI; ++ii) {
        // prefetch 2 stages ahead into ring slot (ii+2)&3
        if (ii + 2 < BI)                 stage(i0 + ii + 2, (ii + 2) & 3);
        else if (ii + 2 == BI && tail)   stage(itail, BI & 3);
        // broadcast l values for this i (static lw index)
        f16x8 lb[4];
        #pragma unroll
        for (int mt = 0; mt < 4; ++mt) {
            f16 v = lw[mt][ii];
            #pragma unroll
            for (int e = 0; e < 8; ++e) lb[mt][e] = v;
        }
        TSTEP(0, ii & 3, true, lb); TSTEP(1, ii & 3, true, lb);
        TSTEP(2, ii & 3, true, lb); TSTEP(3, ii & 3, true, lb);
        if (ii & 1) __syncthreads();    // barrier only after odd stages
    }

    if (tail) {
        const int slot = (BI > 1) ? (BI & 3) : 1;  // tail chunk's ring slot
        if (s == 1) {       // lin-l: overwrite rf with l-row A-frags
            #pragma unroll
            for (int mt = 0; mt < 4; ++mt)
                #pragma unroll
                for (int t = 0; t < 4; ++t)
                    rf[mt][t] = *(const f16x8*)&hin[(size_t)rowL[mt] * DD + t * 32 + q * 8];
        }
        f16x8 dummy[4];
        TSTEP(0, slot, false, dummy); TSTEP(1, slot, false, dummy);
        TSTEP(2, slot, false, dummy); TSTEP(3, slot, false, dummy);
    }
#undef TSTEP

    // ---- store f16 partial tile: C/D layout col=lane&15, row=q*4+reg ----
    f16* pb = part + ((size_t)s * Mrows + m0) * DD + nh * 64;
    #pragma unroll
    for (int mt = 0; mt < 4; ++mt)
        #pragma unroll
        for (int nt = 0; nt < 4; ++nt) {
            int colg = nt * 16 + mrow;
            #pragma unroll
            for (int rr = 0; rr < 4; ++rr) {
                int rowl = wm + mt * 16 + q * 4 + rr;
                pb[(size_t)rowl * DD + colg] = (f16)acc[mt][nt][rr];
            }
        }
}

// ---------------------------------------------------------------------------
// level epilogue: h_out = f16(tanh(sum_s part[s] + bias))
// ---------------------------------------------------------------------------
__global__ void epi_level(const f16* __restrict__ part, const float* __restrict__ bias,
                          f16* __restrict__ hout, int Mrows, int S)
{
    int idx = (blockIdx.x * 256 + threadIdx.x) * 8;
    size_t stride = (size_t)Mrows * DD;
    float sum[8] = {};
    for (int s2 = 0; s2 < S; ++s2) {
        f16x8 v = *(const f16x8*)&part[(size_t)s2 * stride + idx];
        #pragma unroll
        for (int e = 0; e < 8; ++e) sum[e] += (float)v[e];
    }
    int n = idx & 127;
    f16x8 o;
    #pragma unroll
    for (int e = 0; e < 8; ++e) o[e] = (f16)tanhf(sum[e] + bias[n + e]);
    *(f16x8*)&hout[idx] = o;
}

// ---------------------------------------------------------------------------
// final epilogue: leaky_relu(sum_s part + bias) @ Wsm^T + bsm -> log_softmax
// ---------------------------------------------------------------------------
__global__ void fin_epi(const f16* __restrict__ part, const float* __restrict__ bias,
                        const float* __restrict__ Wsm_f, const float* __restrict__ bsm_f,
                        const unsigned short* __restrict__ wv_raw, void* __restrict__ outp, int S)
{
    int lane = threadIdx.x & 63;
    int wv = threadIdx.x >> 6;
    int p = blockIdx.x * 4 + wv;              // 0..511
    size_t stride = (size_t)512 * DD;
    const f16* base = part + (size_t)p * DD;
    float a0 = 0.f, a1 = 0.f;
    for (int s2 = 0; s2 < S; ++s2) {
        a0 += (float)base[(size_t)s2 * stride + lane];
        a1 += (float)base[(size_t)s2 * stride + 64 + lane];
    }
    a0 += bias[lane];      a1 += bias[64 + lane];
    a0 = (a0 > 0.f) ? a0 : 0.01f * a0;
    a1 = (a1 > 0.f) ? a1 : 0.01f * a1;
    float lg[NRELS];
    #pragma unroll
    for (int r = 0; r < NRELS; ++r) {
        float pr = a0 * Wsm_f[r * DD + lane] + a1 * Wsm_f[r * DD + 64 + lane];
        #pragma unroll
        for (int d = 1; d < 64; d <<= 1) pr += __shfl_xor(pr, d, 64);
        lg[r] = pr + bsm_f[r];
    }
    float mx = lg[0];
    #pragma unroll
    for (int r = 1; r < NRELS; ++r) mx = fmaxf(mx, lg[r]);
    float se = 0.f;
    #pragma unroll
    for (int r = 0; r < NRELS; ++r) se += expf(lg[r] - mx);
    float lse = logf(se) + mx;
    if (lane < NRELS) {
        float v = lg[lane] - lse;
        if (detect_bf(wv_raw)) ((__hip_bfloat16*)outp)[p * NRELS + lane] = __float2bfloat16(v);
        else                   ((float*)outp)[p * NRELS + lane] = v;
    }
}

// ---------------------------------------------------------------------------
extern "C" void kernel_launch(void* const* d_in, const int* in_sizes, int n_in,
                              void* d_out, int out_size, void* d_ws, size_t ws_size,
                              hipStream_t stream)
{
    const int* ids = (const int*)d_in[0];

    char* ws = (char*)d_ws;
    f16*   part     = (f16*)ws;                                      // 32 MiB region (f16 partials)
    f16*   h1       = (f16*)(ws + ((size_t)32 << 20));               // 2 MiB
    f16*   h2       = (f16*)(ws + ((size_t)34 << 20));               // 1 MiB
    f16*   h3       = (f16*)(ws + ((size_t)35 << 20));               // 0.5 MiB
    f16*   h4       = (f16*)(ws + ((size_t)35 << 20) + (512 << 10)); // 0.25 MiB
    f16*   WvT      = (f16*)(ws + ((size_t)36 << 20));               // 0.5 MiB
    f16*   Wext     = (f16*)(ws + ((size_t)36 << 20) + (512 << 10)); // 4.0625 MiB
    f16*   Wfin     = Wext + (size_t)NWF;                            // 4.0625 MiB
    float* bias_lvl = (float*)(Wfin + (size_t)NWF);
    float* bias_fin = bias_lvl + 128;
    float* Wsm_f    = bias_fin + 128;
    float* bsm_f    = Wsm_f + NRELS * DD;

    if (ws_size < ((size_t)48 << 20)) return;

    prep_all<<<2145, 256, 0, stream>>>(d_in[1], d_in[2], d_in[3], d_in[4], d_in[5], d_in[6],
                                       d_in[7], d_in[8], d_in[9], d_in[10], d_in[11], d_in[12],
                                       WvT, Wext, Wfin, bias_lvl, bias_fin, Wsm_f, bsm_f);

    // R13 grid schedule (block churn staggers barrier drains) + ring K-loop.
    // level 1 (fused embed-gather): M=8192, 32 mtiles(256) x S=16 x 2 nh -> 1024
    gemm_kernel<8><<<1024, 256, 0, stream>>>(WvT, ids, Wext, part, 8192, 16);
    epi_level<<<512, 256, 0, stream>>>(part, bias_lvl, h1, 8192, 16);
    // level 2: M=4096, 16 mtiles x S=16 x 2 -> 512
    gemm_kernel<8><<<512, 256, 0, stream>>>(h1, nullptr, Wext, part, 4096, 16);
    epi_level<<<256, 256, 0, stream>>>(part, bias_lvl, h2, 4096, 16);
    // level 3: M=2048, 8 mtiles x S=32 x 2 -> 512
    gemm_kernel<4><<<512, 256, 0, stream>>>(h2, nullptr, Wext, part, 2048, 32);
    epi_level<<<128, 256, 0, stream>>>(part, bias_lvl, h3, 2048, 32);
    // level 4: M=1024, 4 mtiles x S=32 x 2 -> 256
    gemm_kernel<4><<<256, 256, 0, stream>>>(h3, nullptr, Wext, part, 1024, 32);
    epi_level<<<64, 256, 0, stream>>>(part, bias_lvl, h4, 1024, 32);
    // final: M=512, 2 mtiles x S=64 x 2 -> 256
    gemm_kernel<2><<<256, 256, 0, stream>>>(h4, nullptr, Wfin, part, 512, 64);
    fin_epi<<<128, 256, 0, stream>>>(part, bias_fin, Wsm_f, bsm_f,
                                     (const unsigned short*)d_in[1], d_out, 64);
}